// Round 2
// baseline (459.201 us; speedup 1.0000x reference)
//
#include <hip/hip_runtime.h>
#include <cmath>

#define T_    128
#define F_    64
#define DI    512
#define DS    16
#define NROW  16384   // 128 seqs * 128 t

// workspace layout (float offsets); dlt and dph share one buffer (k2b reads
// its 32 rows of dlt before the barrier, writes dph after).
#define U_OFF    0u
#define SRES_OFF 8388608u                 // NROW*DI
#define DPH_OFF  16777216u                // NROW*32 (dlt, then dph)
#define DPT_OFF  17301504u                // NROW
#define B_OFF    17317888u                // NROW*16
#define C_OFF    17580032u                // NROW*16  -> end 17842176 (~71.4MB)

__device__ __forceinline__ float silu_f(float v)    { return v / (1.f + __expf(-v)); }
__device__ __forceinline__ float softplus_f(float v){ return (v > 20.f) ? v : log1pf(__expf(v)); }

// ---------------------------------------------------------------------------
// K1: xz = X @ W_in (16384x64 @ 64x1024) + causal depthwise conv4 + SiLU.
// grid (8 t-chunks, 128 seqs), 256 threads. Thread owns 4 consecutive columns
// (float4 W loads + float4 stores); x row values are wave-uniform -> SGPRs.
// Conv halo: 3 extra leading rows accumulated in-register (19 rows total).
// ---------------------------------------------------------------------------
__global__ __launch_bounds__(256) void k1_inproj(
    const float* __restrict__ x, const float* __restrict__ W_in,
    const float* __restrict__ W_conv, const float* __restrict__ b_conv,
    float* __restrict__ u, float* __restrict__ sres)
{
    const int s  = blockIdx.y;
    const int t0 = blockIdx.x * 16;
    const int c4 = threadIdx.x * 4;          // 0..1020
    const float* __restrict__ xrow = x + (size_t)s * (T_ * F_);

    float4 acc[19];
#pragma unroll
    for (int i = 0; i < 19; ++i) acc[i] = make_float4(0.f, 0.f, 0.f, 0.f);

    for (int f0 = 0; f0 < F_; f0 += 8) {
        float4 wv[8];
#pragma unroll
        for (int j = 0; j < 8; ++j)
            wv[j] = *(const float4*)&W_in[(size_t)(f0 + j) * 1024 + c4];
#pragma unroll
        for (int tt = 0; tt < 19; ++tt) {
            const int trow = t0 - 3 + tt;
            if (trow >= 0) {                 // uniform branch (only tc==0 skips)
#pragma unroll
                for (int j = 0; j < 8; ++j) {
                    const float xs = xrow[trow * F_ + f0 + j];   // wave-uniform
                    acc[tt].x = fmaf(xs, wv[j].x, acc[tt].x);
                    acc[tt].y = fmaf(xs, wv[j].y, acc[tt].y);
                    acc[tt].z = fmaf(xs, wv[j].z, acc[tt].z);
                    acc[tt].w = fmaf(xs, wv[j].w, acc[tt].w);
                }
            }
        }
    }

    if (c4 < DI) {   // conv + silu -> u
        const float4 wk0 = *(const float4*)&W_conv[(c4 + 0) * 4];
        const float4 wk1 = *(const float4*)&W_conv[(c4 + 1) * 4];
        const float4 wk2 = *(const float4*)&W_conv[(c4 + 2) * 4];
        const float4 wk3 = *(const float4*)&W_conv[(c4 + 3) * 4];
        const float4 bc  = *(const float4*)&b_conv[c4];
#pragma unroll
        for (int i = 0; i < 16; ++i) {
            float4 pre;
            pre.x = bc.x; pre.y = bc.y; pre.z = bc.z; pre.w = bc.w;
            pre.x = fmaf(wk0.x, acc[i].x, pre.x); pre.x = fmaf(wk0.y, acc[i+1].x, pre.x);
            pre.x = fmaf(wk0.z, acc[i+2].x, pre.x); pre.x = fmaf(wk0.w, acc[i+3].x, pre.x);
            pre.y = fmaf(wk1.x, acc[i].y, pre.y); pre.y = fmaf(wk1.y, acc[i+1].y, pre.y);
            pre.y = fmaf(wk1.z, acc[i+2].y, pre.y); pre.y = fmaf(wk1.w, acc[i+3].y, pre.y);
            pre.z = fmaf(wk2.x, acc[i].z, pre.z); pre.z = fmaf(wk2.y, acc[i+1].z, pre.z);
            pre.z = fmaf(wk2.z, acc[i+2].z, pre.z); pre.z = fmaf(wk2.w, acc[i+3].z, pre.z);
            pre.w = fmaf(wk3.x, acc[i].w, pre.w); pre.w = fmaf(wk3.y, acc[i+1].w, pre.w);
            pre.w = fmaf(wk3.z, acc[i+2].w, pre.w); pre.w = fmaf(wk3.w, acc[i+3].w, pre.w);
            float4 o;
            o.x = silu_f(pre.x); o.y = silu_f(pre.y);
            o.z = silu_f(pre.z); o.w = silu_f(pre.w);
            *(float4*)&u[(size_t)(s * T_ + t0 + i) * DI + c4] = o;
        }
    } else {         // silu(res) -> sres
        const int c = c4 - DI;
#pragma unroll
        for (int i = 0; i < 16; ++i) {
            float4 o;
            o.x = silu_f(acc[i + 3].x); o.y = silu_f(acc[i + 3].y);
            o.z = silu_f(acc[i + 3].z); o.w = silu_f(acc[i + 3].w);
            *(float4*)&sres[(size_t)(s * T_ + t0 + i) * DI + c] = o;
        }
    }
}

// ---------------------------------------------------------------------------
// K2a: xdbl = u @ W_xproj  (M=16384, N=64, K=512) -> dlt / B / C.
// 256 blocks x 256 thr. Wave w owns 16 rows (uniform via readfirstlane ->
// u rows come through the scalar pipe); lane owns column c; W chunk in VGPRs.
// ---------------------------------------------------------------------------
__global__ __launch_bounds__(256) void k2a_xproj(
    const float* __restrict__ u, const float* __restrict__ W_xp,
    float* __restrict__ dlt, float* __restrict__ Bb, float* __restrict__ Cb)
{
    const int c  = threadIdx.x & 63;
    const int rw = __builtin_amdgcn_readfirstlane(threadIdx.x >> 6);
    const int r0 = blockIdx.x * 64 + rw * 16;

    float acc[16];
#pragma unroll
    for (int i = 0; i < 16; ++i) acc[i] = 0.f;

    for (int k0 = 0; k0 < DI; k0 += 8) {
        float w[8];
#pragma unroll
        for (int j = 0; j < 8; ++j) w[j] = W_xp[(size_t)(k0 + j) * 64 + c];
#pragma unroll
        for (int rr = 0; rr < 16; ++rr) {
            const float* ur = u + (size_t)(r0 + rr) * DI + k0;   // wave-uniform
#pragma unroll
            for (int j = 0; j < 8; ++j) acc[rr] = fmaf(ur[j], w[j], acc[rr]);
        }
    }
#pragma unroll
    for (int rr = 0; rr < 16; ++rr) {
        const int r = r0 + rr;
        const float v = acc[rr];
        if (c < 32)      dlt[(size_t)r * 32 + c]      = v;
        else if (c < 48) Bb [(size_t)r * DS + c - 32] = v;
        else             Cb [(size_t)r * DS + c - 48] = v;
    }
}

// ---------------------------------------------------------------------------
// K2b: delta = softplus(dlt @ W_dt + b_dt); dpt = rowsum(delta);
// dph[r][d<32] = (rowsum - headsum) + sum_j delta[j]*adj[j][d].
// 512 blocks x 32 rows. Thread owns d and d+256 (W_dt cols in registers).
// dph overwrites the dlt buffer (reads complete before the barrier).
// ---------------------------------------------------------------------------
__global__ __launch_bounds__(256) void k2b_delta(
    const float* __restrict__ dlt_in, const float* __restrict__ W_dt,
    const float* __restrict__ b_dt, const int* __restrict__ adj,
    float* __restrict__ dph, float* __restrict__ dpt)
{
    __shared__ float head_l[32][33];
    __shared__ float scrS[4][32];
    __shared__ float stail_l[32];
    __shared__ float adj_l[1024];

    const int tid  = threadIdx.x;
    const int lane = tid & 63, wv4 = tid >> 6;
    const int r0   = blockIdx.x * 32;
    const int d0 = tid, d1 = tid + 256;

    for (int i = tid; i < 1024; i += 256) adj_l[i] = (float)adj[i];

    float wdt0[32], wdt1[32];
#pragma unroll
    for (int j = 0; j < 32; ++j) {
        wdt0[j] = W_dt[j * DI + d0];
        wdt1[j] = W_dt[j * DI + d1];
    }
    const float b0 = b_dt[d0], b1 = b_dt[d1];

    for (int r = 0; r < 32; ++r) {
        const float* dr = dlt_in + (size_t)(r0 + r) * 32;   // wave-uniform
        float a0 = b0, a1 = b1;
#pragma unroll
        for (int j = 0; j < 32; ++j) {
            const float dl = dr[j];
            a0 = fmaf(dl, wdt0[j], a0);
            a1 = fmaf(dl, wdt1[j], a1);
        }
        const float e0 = softplus_f(a0), e1 = softplus_f(a1);
        if (tid < 32) head_l[r][tid] = e0;
        float v = e0 + e1;
#pragma unroll
        for (int off = 32; off > 0; off >>= 1) v += __shfl_down(v, off, 64);
        if (lane == 0) scrS[wv4][r] = v;
    }
    __syncthreads();
    if (tid < 32) {
        const int r = tid;
        const float st = scrS[0][r] + scrS[1][r] + scrS[2][r] + scrS[3][r];
        dpt[r0 + r] = st;
        float sh = 0.f;
#pragma unroll
        for (int j = 0; j < 32; ++j) sh += head_l[r][j];
        stail_l[r] = st - sh;
    }
    __syncthreads();
#pragma unroll
    for (int k = 0; k < 4; ++k) {
        const int o = k * 256 + tid;
        const int r = o >> 5, dd = o & 31;
        float a = stail_l[r];
#pragma unroll
        for (int j = 0; j < 32; ++j) a = fmaf(head_l[r][j], adj_l[j * 32 + dd], a);
        dph[(size_t)(r0 + r) * 32 + dd] = a;
    }
}

// ---------------------------------------------------------------------------
// K3: selective scan, 1 channel/thread, h[16] in registers, explicit t+1
// prefetch of u/gate/dp so the dependent-load latency overlaps compute.
// B/C rows are wave-uniform -> scalar loads. Writes gated y over sres.
// ---------------------------------------------------------------------------
__global__ __launch_bounds__(256) void k3_scan(
    const float* __restrict__ u, float* __restrict__ sres_y,
    const float* __restrict__ dph, const float* __restrict__ dpt,
    const float* __restrict__ Bb, const float* __restrict__ Cb,
    const float* __restrict__ A_log, const float* __restrict__ Dvec)
{
    const int s = blockIdx.y;
    const int d = blockIdx.x * 256 + threadIdx.x;
    float A[DS];
#pragma unroll
    for (int n = 0; n < DS; ++n) A[n] = -__expf(A_log[d * DS + n]);
    const float Dd = Dvec[d];
    const bool isHead = (d < 32);

    const size_t rb = (size_t)s * T_;
    const float* up   = u      + rb * DI + d;
    float*       gp   = sres_y + rb * DI + d;
    const float* dphp = dph + rb * 32 + d;
    const float* dptp = dpt + rb;
    const float* Bp   = Bb + rb * DS;
    const float* Cp   = Cb + rb * DS;

    float h[DS];
#pragma unroll
    for (int n = 0; n < DS; ++n) h[n] = 0.f;

    float u_n  = up[0];
    float g_n  = gp[0];
    float dp_n = isHead ? dphp[0] : dptp[0];

    for (int t = 0; t < T_; ++t) {
        const float u_c = u_n, g_c = g_n, dp_c = dp_n;
        if (t + 1 < T_) {            // prefetch next step
            u_n  = up[(size_t)(t + 1) * DI];
            g_n  = gp[(size_t)(t + 1) * DI];
            dp_n = isHead ? dphp[(size_t)(t + 1) * 32] : dptp[t + 1];
        }
        const float du = dp_c * u_c;
        float y0 = 0.f, y1 = 0.f, y2 = 0.f, y3 = 0.f;
#pragma unroll
        for (int n = 0; n < DS; n += 4) {
            const float e0 = __expf(dp_c * A[n + 0]);
            const float e1 = __expf(dp_c * A[n + 1]);
            const float e2 = __expf(dp_c * A[n + 2]);
            const float e3 = __expf(dp_c * A[n + 3]);
            h[n + 0] = fmaf(e0, h[n + 0], du * Bp[t * DS + n + 0]);
            h[n + 1] = fmaf(e1, h[n + 1], du * Bp[t * DS + n + 1]);
            h[n + 2] = fmaf(e2, h[n + 2], du * Bp[t * DS + n + 2]);
            h[n + 3] = fmaf(e3, h[n + 3], du * Bp[t * DS + n + 3]);
            y0 = fmaf(h[n + 0], Cp[t * DS + n + 0], y0);
            y1 = fmaf(h[n + 1], Cp[t * DS + n + 1], y1);
            y2 = fmaf(h[n + 2], Cp[t * DS + n + 2], y2);
            y3 = fmaf(h[n + 3], Cp[t * DS + n + 3], y3);
        }
        const float yf = (((y0 + y1) + (y2 + y3)) + u_c * Dd) * g_c;
        gp[(size_t)t * DI] = yf;
    }
}

// ---------------------------------------------------------------------------
// K4: out = y @ W_out (M=16384, N=64, K=512). Same wave-row / lane-col
// scalar-pipe structure as k2a; no LDS, no barriers.
// ---------------------------------------------------------------------------
__global__ __launch_bounds__(256) void k4_out(
    const float* __restrict__ y, const float* __restrict__ W_out,
    float* __restrict__ out)
{
    const int c  = threadIdx.x & 63;
    const int rw = __builtin_amdgcn_readfirstlane(threadIdx.x >> 6);
    const int r0 = blockIdx.x * 64 + rw * 16;

    float acc[16];
#pragma unroll
    for (int i = 0; i < 16; ++i) acc[i] = 0.f;

    for (int k0 = 0; k0 < DI; k0 += 8) {
        float w[8];
#pragma unroll
        for (int j = 0; j < 8; ++j) w[j] = W_out[(size_t)(k0 + j) * 64 + c];
#pragma unroll
        for (int rr = 0; rr < 16; ++rr) {
            const float* yr = y + (size_t)(r0 + rr) * DI + k0;   // wave-uniform
#pragma unroll
            for (int j = 0; j < 8; ++j) acc[rr] = fmaf(yr[j], w[j], acc[rr]);
        }
    }
#pragma unroll
    for (int rr = 0; rr < 16; ++rr)
        out[(size_t)(r0 + rr) * 64 + c] = acc[rr];
}

extern "C" void kernel_launch(void* const* d_in, const int* in_sizes, int n_in,
                              void* d_out, int out_size, void* d_ws, size_t ws_size,
                              hipStream_t stream)
{
    const float* x      = (const float*)d_in[0];
    const int*   adj    = (const int*)  d_in[1];
    const float* W_in   = (const float*)d_in[2];
    const float* W_conv = (const float*)d_in[3];
    const float* b_conv = (const float*)d_in[4];
    const float* W_xp   = (const float*)d_in[5];
    const float* W_dt   = (const float*)d_in[6];
    const float* b_dt   = (const float*)d_in[7];
    const float* A_log  = (const float*)d_in[8];
    const float* Dvec   = (const float*)d_in[9];
    const float* W_out  = (const float*)d_in[10];

    float* ws   = (float*)d_ws;
    float* u    = ws + U_OFF;
    float* sres = ws + SRES_OFF;   // becomes gated y after k3
    float* dB   = ws + DPH_OFF;    // dlt, then dph
    float* dpt  = ws + DPT_OFF;
    float* Bb   = ws + B_OFF;
    float* Cb   = ws + C_OFF;
    float* out  = (float*)d_out;

    k1_inproj<<<dim3(8, 128), 256, 0, stream>>>(x, W_in, W_conv, b_conv, u, sres);
    k2a_xproj<<<dim3(256),    256, 0, stream>>>(u, W_xp, dB, Bb, Cb);
    k2b_delta<<<dim3(512),    256, 0, stream>>>(dB, W_dt, b_dt, adj, dB, dpt);
    k3_scan  <<<dim3(2, 128), 256, 0, stream>>>(u, sres, dB, dpt, Bb, Cb, A_log, Dvec);
    k4_out   <<<dim3(256),    256, 0, stream>>>(sres, W_out, out);
}

// Round 3
// 323.902 us; speedup vs baseline: 1.4177x; 1.4177x over previous
//
#include <hip/hip_runtime.h>
#include <cmath>

#define T_    128
#define F_    64
#define DI    512
#define DS    16
#define NROW  16384   // 128 seqs * 128 t

// workspace layout (float offsets); dlt and dph share one buffer (k2b stages
// its 32 rows of dlt into LDS before writing dph over them).
#define U_OFF    0u
#define SRES_OFF 8388608u                 // NROW*DI
#define DPH_OFF  16777216u                // NROW*32 (dlt, then dph)
#define DPT_OFF  17301504u                // NROW
#define B_OFF    17317888u                // NROW*16
#define C_OFF    17580032u                // NROW*16  -> end 17842176 (~71.4MB)

__device__ __forceinline__ float silu_f(float v)    { return v / (1.f + __expf(-v)); }
__device__ __forceinline__ float softplus_f(float v){ return (v > 20.f) ? v : log1pf(__expf(v)); }

// ---------------------------------------------------------------------------
// K1: xz = X @ W_in (16384x64 @ 64x1024) + causal depthwise conv4 + SiLU.
// grid (8 t-chunks, 128 seqs) x 256 thr. Thread owns 4 cols x 19 t-rows
// (16 outputs + 3-row conv halo, halo zero-filled at t<0 during staging).
// x tile lives in LDS (broadcast b128 reads); W column quad in VGPRs.
// ---------------------------------------------------------------------------
__global__ __launch_bounds__(256) void k1_inproj(
    const float* __restrict__ x, const float* __restrict__ W_in,
    const float* __restrict__ W_conv, const float* __restrict__ b_conv,
    float* __restrict__ u, float* __restrict__ sres)
{
    __shared__ float x_l[19][64];            // 4.75 KB
    const int s  = blockIdx.y;
    const int t0 = blockIdx.x * 16;
    const int c4 = threadIdx.x * 4;          // 0..1020

    // stage x rows t0-3 .. t0+15 (zeros for t<0)
    for (int i = threadIdx.x; i < 19 * 16; i += 256) {
        const int row = i >> 4, col = (i & 15) * 4;
        const int trow = t0 - 3 + row;
        float4 v = make_float4(0.f, 0.f, 0.f, 0.f);
        if (trow >= 0) v = *(const float4*)&x[(size_t)s * (T_ * F_) + trow * F_ + col];
        *(float4*)&x_l[row][col] = v;
    }
    __syncthreads();

    float4 acc[19];
#pragma unroll
    for (int i = 0; i < 19; ++i) acc[i] = make_float4(0.f, 0.f, 0.f, 0.f);

    for (int f0 = 0; f0 < F_; f0 += 8) {
        float4 wv[8];
#pragma unroll
        for (int j = 0; j < 8; ++j)
            wv[j] = *(const float4*)&W_in[(size_t)(f0 + j) * 1024 + c4];
#pragma unroll
        for (int tt = 0; tt < 19; ++tt) {
            const float4 xa = *(const float4*)&x_l[tt][f0];
            const float4 xb = *(const float4*)&x_l[tt][f0 + 4];
            float4 a = acc[tt];
            a.x = fmaf(xa.x, wv[0].x, a.x); a.y = fmaf(xa.x, wv[0].y, a.y);
            a.z = fmaf(xa.x, wv[0].z, a.z); a.w = fmaf(xa.x, wv[0].w, a.w);
            a.x = fmaf(xa.y, wv[1].x, a.x); a.y = fmaf(xa.y, wv[1].y, a.y);
            a.z = fmaf(xa.y, wv[1].z, a.z); a.w = fmaf(xa.y, wv[1].w, a.w);
            a.x = fmaf(xa.z, wv[2].x, a.x); a.y = fmaf(xa.z, wv[2].y, a.y);
            a.z = fmaf(xa.z, wv[2].z, a.z); a.w = fmaf(xa.z, wv[2].w, a.w);
            a.x = fmaf(xa.w, wv[3].x, a.x); a.y = fmaf(xa.w, wv[3].y, a.y);
            a.z = fmaf(xa.w, wv[3].z, a.z); a.w = fmaf(xa.w, wv[3].w, a.w);
            a.x = fmaf(xb.x, wv[4].x, a.x); a.y = fmaf(xb.x, wv[4].y, a.y);
            a.z = fmaf(xb.x, wv[4].z, a.z); a.w = fmaf(xb.x, wv[4].w, a.w);
            a.x = fmaf(xb.y, wv[5].x, a.x); a.y = fmaf(xb.y, wv[5].y, a.y);
            a.z = fmaf(xb.y, wv[5].z, a.z); a.w = fmaf(xb.y, wv[5].w, a.w);
            a.x = fmaf(xb.z, wv[6].x, a.x); a.y = fmaf(xb.z, wv[6].y, a.y);
            a.z = fmaf(xb.z, wv[6].z, a.z); a.w = fmaf(xb.z, wv[6].w, a.w);
            a.x = fmaf(xb.w, wv[7].x, a.x); a.y = fmaf(xb.w, wv[7].y, a.y);
            a.z = fmaf(xb.w, wv[7].z, a.z); a.w = fmaf(xb.w, wv[7].w, a.w);
            acc[tt] = a;
        }
    }

    if (c4 < DI) {   // conv + silu -> u
        const float4 wk0 = *(const float4*)&W_conv[(c4 + 0) * 4];
        const float4 wk1 = *(const float4*)&W_conv[(c4 + 1) * 4];
        const float4 wk2 = *(const float4*)&W_conv[(c4 + 2) * 4];
        const float4 wk3 = *(const float4*)&W_conv[(c4 + 3) * 4];
        const float4 bc  = *(const float4*)&b_conv[c4];
#pragma unroll
        for (int i = 0; i < 16; ++i) {
            float4 pre;
            pre.x = bc.x; pre.y = bc.y; pre.z = bc.z; pre.w = bc.w;
            pre.x = fmaf(wk0.x, acc[i].x, pre.x); pre.x = fmaf(wk0.y, acc[i+1].x, pre.x);
            pre.x = fmaf(wk0.z, acc[i+2].x, pre.x); pre.x = fmaf(wk0.w, acc[i+3].x, pre.x);
            pre.y = fmaf(wk1.x, acc[i].y, pre.y); pre.y = fmaf(wk1.y, acc[i+1].y, pre.y);
            pre.y = fmaf(wk1.z, acc[i+2].y, pre.y); pre.y = fmaf(wk1.w, acc[i+3].y, pre.y);
            pre.z = fmaf(wk2.x, acc[i].z, pre.z); pre.z = fmaf(wk2.y, acc[i+1].z, pre.z);
            pre.z = fmaf(wk2.z, acc[i+2].z, pre.z); pre.z = fmaf(wk2.w, acc[i+3].z, pre.z);
            pre.w = fmaf(wk3.x, acc[i].w, pre.w); pre.w = fmaf(wk3.y, acc[i+1].w, pre.w);
            pre.w = fmaf(wk3.z, acc[i+2].w, pre.w); pre.w = fmaf(wk3.w, acc[i+3].w, pre.w);
            float4 o;
            o.x = silu_f(pre.x); o.y = silu_f(pre.y);
            o.z = silu_f(pre.z); o.w = silu_f(pre.w);
            *(float4*)&u[(size_t)(s * T_ + t0 + i) * DI + c4] = o;
        }
    } else {         // silu(res) -> sres
        const int c = c4 - DI;
#pragma unroll
        for (int i = 0; i < 16; ++i) {
            float4 o;
            o.x = silu_f(acc[i + 3].x); o.y = silu_f(acc[i + 3].y);
            o.z = silu_f(acc[i + 3].z); o.w = silu_f(acc[i + 3].w);
            *(float4*)&sres[(size_t)(s * T_ + t0 + i) * DI + c] = o;
        }
    }
}

// ---------------------------------------------------------------------------
// K2a: xdbl = u @ W_xproj (M=16384, N=64, K=512) -> dlt / B / C.
// Classic LDS GEMM: 64x64 output tile, K-chunks of 64, thread = 4r x 4c.
// y_l padded to 68 (2-way max on b128 row reads = free); W rows read as
// contiguous 256B broadcast.
// ---------------------------------------------------------------------------
__global__ __launch_bounds__(256) void k2a_xproj(
    const float* __restrict__ uin, const float* __restrict__ W_xp,
    float* __restrict__ dlt, float* __restrict__ Bb, float* __restrict__ Cb)
{
    __shared__ float y_l[64][68];   // 17.4 KB
    __shared__ float w_l[64][64];   // 16 KB
    const int tid = threadIdx.x;
    const int rq = tid >> 4, cq = tid & 15;
    const int r0 = blockIdx.x * 64;
    const int c4 = cq * 4;

    float4 acc[4];
#pragma unroll
    for (int i = 0; i < 4; ++i) acc[i] = make_float4(0.f, 0.f, 0.f, 0.f);

    for (int kc = 0; kc < DI; kc += 64) {
        for (int i = tid; i < 64 * 16; i += 256) {
            const int row = i >> 4, cc = (i & 15) * 4;
            *(float4*)&y_l[row][cc] = *(const float4*)&uin[(size_t)(r0 + row) * DI + kc + cc];
            *(float4*)&w_l[row][cc] = *(const float4*)&W_xp[(size_t)(kc + row) * 64 + cc];
        }
        __syncthreads();
#pragma unroll 4
        for (int kk = 0; kk < 64; kk += 4) {
            float4 yv[4], wv[4];
#pragma unroll
            for (int i = 0; i < 4; ++i) yv[i] = *(const float4*)&y_l[rq * 4 + i][kk];
#pragma unroll
            for (int j = 0; j < 4; ++j) wv[j] = *(const float4*)&w_l[kk + j][c4];
#pragma unroll
            for (int i = 0; i < 4; ++i) {
                float4 a = acc[i];
                a.x = fmaf(yv[i].x, wv[0].x, a.x); a.y = fmaf(yv[i].x, wv[0].y, a.y);
                a.z = fmaf(yv[i].x, wv[0].z, a.z); a.w = fmaf(yv[i].x, wv[0].w, a.w);
                a.x = fmaf(yv[i].y, wv[1].x, a.x); a.y = fmaf(yv[i].y, wv[1].y, a.y);
                a.z = fmaf(yv[i].y, wv[1].z, a.z); a.w = fmaf(yv[i].y, wv[1].w, a.w);
                a.x = fmaf(yv[i].z, wv[2].x, a.x); a.y = fmaf(yv[i].z, wv[2].y, a.y);
                a.z = fmaf(yv[i].z, wv[2].z, a.z); a.w = fmaf(yv[i].z, wv[2].w, a.w);
                a.x = fmaf(yv[i].w, wv[3].x, a.x); a.y = fmaf(yv[i].w, wv[3].y, a.y);
                a.z = fmaf(yv[i].w, wv[3].z, a.z); a.w = fmaf(yv[i].w, wv[3].w, a.w);
                acc[i] = a;
            }
        }
        __syncthreads();
    }
#pragma unroll
    for (int i = 0; i < 4; ++i) {
        const int r = r0 + rq * 4 + i;
        if (c4 < 32)      *(float4*)&dlt[(size_t)r * 32 + c4]        = acc[i];
        else if (c4 < 48) *(float4*)&Bb [(size_t)r * DS + (c4 - 32)] = acc[i];
        else              *(float4*)&Cb [(size_t)r * DS + (c4 - 48)] = acc[i];
    }
}

// ---------------------------------------------------------------------------
// K2b: delta = softplus(dlt @ W_dt + b_dt); dpt = rowsum(delta);
// dph[r][d<32] = (rowsum - headsum) + sum_j delta[j]*adj[j][d].
// 512 blocks x 32 rows. dlt tile staged in LDS (broadcast b128 reads);
// W_dt cols (d=tid, d=tid+256) in registers. dph overwrites dlt buffer.
// ---------------------------------------------------------------------------
__global__ __launch_bounds__(256) void k2b_delta(
    const float* __restrict__ dlt_in, const float* __restrict__ W_dt,
    const float* __restrict__ b_dt, const int* __restrict__ adj,
    float* __restrict__ dph, float* __restrict__ dpt)
{
    __shared__ float dl_l[32][32];
    __shared__ float head_l[32][33];
    __shared__ float scrS[4][32];
    __shared__ float stail_l[32];
    __shared__ float adj_l[1024];

    const int tid  = threadIdx.x;
    const int lane = tid & 63, wv4 = tid >> 6;
    const int r0   = blockIdx.x * 32;

    {   // stage dlt tile (1024 floats) + adj
        const int row = tid >> 3, cc = (tid & 7) * 4;
        *(float4*)&dl_l[row][cc] = *(const float4*)&dlt_in[(size_t)(r0 + row) * 32 + cc];
        for (int i = tid; i < 1024; i += 256) adj_l[i] = (float)adj[i];
    }

    float wdt0[32], wdt1[32];
#pragma unroll
    for (int j = 0; j < 32; ++j) {
        wdt0[j] = W_dt[j * DI + tid];
        wdt1[j] = W_dt[j * DI + tid + 256];
    }
    const float b0 = b_dt[tid], b1 = b_dt[tid + 256];
    __syncthreads();

    for (int r = 0; r < 32; ++r) {
        float a0 = b0, a1 = b1;
#pragma unroll
        for (int jq = 0; jq < 8; ++jq) {
            const float4 dv = *(const float4*)&dl_l[r][jq * 4];
            a0 = fmaf(dv.x, wdt0[jq*4+0], a0); a1 = fmaf(dv.x, wdt1[jq*4+0], a1);
            a0 = fmaf(dv.y, wdt0[jq*4+1], a0); a1 = fmaf(dv.y, wdt1[jq*4+1], a1);
            a0 = fmaf(dv.z, wdt0[jq*4+2], a0); a1 = fmaf(dv.z, wdt1[jq*4+2], a1);
            a0 = fmaf(dv.w, wdt0[jq*4+3], a0); a1 = fmaf(dv.w, wdt1[jq*4+3], a1);
        }
        const float e0 = softplus_f(a0), e1 = softplus_f(a1);
        if (tid < 32) head_l[r][tid] = e0;
        float v = e0 + e1;
#pragma unroll
        for (int off = 32; off > 0; off >>= 1) v += __shfl_down(v, off, 64);
        if (lane == 0) scrS[wv4][r] = v;
    }
    __syncthreads();
    if (tid < 32) {
        const int r = tid;
        const float st = scrS[0][r] + scrS[1][r] + scrS[2][r] + scrS[3][r];
        dpt[r0 + r] = st;
        float sh = 0.f;
#pragma unroll
        for (int j = 0; j < 32; ++j) sh += head_l[r][j];
        stail_l[r] = st - sh;
    }
    __syncthreads();
#pragma unroll
    for (int k = 0; k < 4; ++k) {
        const int o = k * 256 + tid;
        const int r = o >> 5, dd = o & 31;
        float a = stail_l[r];
#pragma unroll
        for (int j = 0; j < 32; ++j) a = fmaf(head_l[r][j], adj_l[j * 32 + dd], a);
        dph[(size_t)(r0 + r) * 32 + dd] = a;
    }
}

// ---------------------------------------------------------------------------
// K3: selective scan, 1 channel/thread, h[16] in registers. Deep software
// pipeline: u/gate/dp ring-buffered 4 steps ahead, B/C (float4 x4) double-
// buffered 2 steps ahead — all addresses are computation-independent, so the
// only serial chain is the h update itself. Writes gated y over sres.
// ---------------------------------------------------------------------------
__global__ __launch_bounds__(256) void k3_scan(
    const float* __restrict__ u, float* __restrict__ sres_y,
    const float* __restrict__ dph, const float* __restrict__ dpt,
    const float* __restrict__ Bb, const float* __restrict__ Cb,
    const float* __restrict__ A_log, const float* __restrict__ Dvec)
{
    const int s = blockIdx.y;
    const int d = blockIdx.x * 256 + threadIdx.x;
    float A[DS];
#pragma unroll
    for (int n = 0; n < DS; ++n) A[n] = -__expf(A_log[d * DS + n]);
    const float Dd = Dvec[d];
    const bool isHead = (d < 32);

    const size_t rb = (size_t)s * T_;
    const float* up   = u      + rb * DI + d;
    float*       gp   = sres_y + rb * DI + d;
    const float* dphp = dph + rb * 32 + d;
    const float* dptp = dpt + rb;
    const float4* Bp  = (const float4*)(Bb + rb * DS);
    const float4* Cp  = (const float4*)(Cb + rb * DS);

    float h[DS];
#pragma unroll
    for (int n = 0; n < DS; ++n) h[n] = 0.f;

    float ub[4], gb[4], dpb[4];
#pragma unroll
    for (int j = 0; j < 4; ++j) {
        ub[j]  = up[(size_t)j * DI];
        gb[j]  = gp[(size_t)j * DI];
        dpb[j] = isHead ? dphp[(size_t)j * 32] : dptp[j];
    }
    float4 bB[2][4], bC[2][4];
#pragma unroll
    for (int j = 0; j < 2; ++j)
#pragma unroll
        for (int q = 0; q < 4; ++q) { bB[j][q] = Bp[j * 4 + q]; bC[j][q] = Cp[j * 4 + q]; }

    for (int t = 0; t < T_; t += 4) {
#pragma unroll
        for (int j = 0; j < 4; ++j) {
            const int tc = t + j;
            const float u_c = ub[j], g_c = gb[j], dp_c = dpb[j];
            const float du = dp_c * u_c;
            float y0 = 0.f, y1 = 0.f, y2 = 0.f, y3 = 0.f;
#pragma unroll
            for (int q = 0; q < 4; ++q) {
                const float4 Bv = bB[j & 1][q];
                const float4 Cv = bC[j & 1][q];
                const int n = q * 4;
                const float e0 = __expf(dp_c * A[n + 0]);
                const float e1 = __expf(dp_c * A[n + 1]);
                const float e2 = __expf(dp_c * A[n + 2]);
                const float e3 = __expf(dp_c * A[n + 3]);
                h[n + 0] = fmaf(e0, h[n + 0], du * Bv.x);
                h[n + 1] = fmaf(e1, h[n + 1], du * Bv.y);
                h[n + 2] = fmaf(e2, h[n + 2], du * Bv.z);
                h[n + 3] = fmaf(e3, h[n + 3], du * Bv.w);
                y0 = fmaf(h[n + 0], Cv.x, y0);
                y1 = fmaf(h[n + 1], Cv.y, y1);
                y2 = fmaf(h[n + 2], Cv.z, y2);
                y3 = fmaf(h[n + 3], Cv.w, y3);
            }
            const float yf = (((y0 + y1) + (y2 + y3)) + u_c * Dd) * g_c;
            gp[(size_t)tc * DI] = yf;
            // refill pipeline (slot j reused at tc+4; B/C slot reused at tc+2)
            if (tc + 4 < T_) {
                ub[j]  = up[(size_t)(tc + 4) * DI];
                gb[j]  = gp[(size_t)(tc + 4) * DI];
                dpb[j] = isHead ? dphp[(size_t)(tc + 4) * 32] : dptp[tc + 4];
            }
            if (tc + 2 < T_) {
#pragma unroll
                for (int q = 0; q < 4; ++q) {
                    bB[j & 1][q] = Bp[(tc + 2) * 4 + q];
                    bC[j & 1][q] = Cp[(tc + 2) * 4 + q];
                }
            }
        }
    }
}

// ---------------------------------------------------------------------------
// K4: out = y @ W_out (M=16384, N=64, K=512). Same LDS GEMM as k2a.
// ---------------------------------------------------------------------------
__global__ __launch_bounds__(256) void k4_out(
    const float* __restrict__ y, const float* __restrict__ W_out,
    float* __restrict__ out)
{
    __shared__ float y_l[64][68];
    __shared__ float w_l[64][64];
    const int tid = threadIdx.x;
    const int rq = tid >> 4, cq = tid & 15;
    const int r0 = blockIdx.x * 64;
    const int c4 = cq * 4;

    float4 acc[4];
#pragma unroll
    for (int i = 0; i < 4; ++i) acc[i] = make_float4(0.f, 0.f, 0.f, 0.f);

    for (int kc = 0; kc < DI; kc += 64) {
        for (int i = tid; i < 64 * 16; i += 256) {
            const int row = i >> 4, cc = (i & 15) * 4;
            *(float4*)&y_l[row][cc] = *(const float4*)&y[(size_t)(r0 + row) * DI + kc + cc];
            *(float4*)&w_l[row][cc] = *(const float4*)&W_out[(size_t)(kc + row) * 64 + cc];
        }
        __syncthreads();
#pragma unroll 4
        for (int kk = 0; kk < 64; kk += 4) {
            float4 yv[4], wv[4];
#pragma unroll
            for (int i = 0; i < 4; ++i) yv[i] = *(const float4*)&y_l[rq * 4 + i][kk];
#pragma unroll
            for (int j = 0; j < 4; ++j) wv[j] = *(const float4*)&w_l[kk + j][c4];
#pragma unroll
            for (int i = 0; i < 4; ++i) {
                float4 a = acc[i];
                a.x = fmaf(yv[i].x, wv[0].x, a.x); a.y = fmaf(yv[i].x, wv[0].y, a.y);
                a.z = fmaf(yv[i].x, wv[0].z, a.z); a.w = fmaf(yv[i].x, wv[0].w, a.w);
                a.x = fmaf(yv[i].y, wv[1].x, a.x); a.y = fmaf(yv[i].y, wv[1].y, a.y);
                a.z = fmaf(yv[i].y, wv[1].z, a.z); a.w = fmaf(yv[i].y, wv[1].w, a.w);
                a.x = fmaf(yv[i].z, wv[2].x, a.x); a.y = fmaf(yv[i].z, wv[2].y, a.y);
                a.z = fmaf(yv[i].z, wv[2].z, a.z); a.w = fmaf(yv[i].z, wv[2].w, a.w);
                a.x = fmaf(yv[i].w, wv[3].x, a.x); a.y = fmaf(yv[i].w, wv[3].y, a.y);
                a.z = fmaf(yv[i].w, wv[3].z, a.z); a.w = fmaf(yv[i].w, wv[3].w, a.w);
                acc[i] = a;
            }
        }
        __syncthreads();
    }
#pragma unroll
    for (int i = 0; i < 4; ++i)
        *(float4*)&out[(size_t)(r0 + rq * 4 + i) * 64 + c4] = acc[i];
}

extern "C" void kernel_launch(void* const* d_in, const int* in_sizes, int n_in,
                              void* d_out, int out_size, void* d_ws, size_t ws_size,
                              hipStream_t stream)
{
    const float* x      = (const float*)d_in[0];
    const int*   adj    = (const int*)  d_in[1];
    const float* W_in   = (const float*)d_in[2];
    const float* W_conv = (const float*)d_in[3];
    const float* b_conv = (const float*)d_in[4];
    const float* W_xp   = (const float*)d_in[5];
    const float* W_dt   = (const float*)d_in[6];
    const float* b_dt   = (const float*)d_in[7];
    const float* A_log  = (const float*)d_in[8];
    const float* Dvec   = (const float*)d_in[9];
    const float* W_out  = (const float*)d_in[10];

    float* ws   = (float*)d_ws;
    float* u    = ws + U_OFF;
    float* sres = ws + SRES_OFF;   // becomes gated y after k3
    float* dB   = ws + DPH_OFF;    // dlt, then dph
    float* dpt  = ws + DPT_OFF;
    float* Bb   = ws + B_OFF;
    float* Cb   = ws + C_OFF;
    float* out  = (float*)d_out;

    k1_inproj<<<dim3(8, 128), 256, 0, stream>>>(x, W_in, W_conv, b_conv, u, sres);
    k2a_xproj<<<dim3(256),    256, 0, stream>>>(u, W_xp, dB, Bb, Cb);
    k2b_delta<<<dim3(512),    256, 0, stream>>>(dB, W_dt, b_dt, adj, dB, dpt);
    k3_scan  <<<dim3(2, 128), 256, 0, stream>>>(u, sres, dB, dpt, Bb, Cb, A_log, Dvec);
    k4_out   <<<dim3(256),    256, 0, stream>>>(sres, W_out, out);
}